// Round 4
// baseline (2203.641 us; speedup 1.0000x reference)
//
#include <hip/hip_runtime.h>
#include <hip/hip_bf16.h>
#include <math.h>

// B=32 graphs, N=256 nodes/graph, D=128.
#define DD   128
#define NPG  256
#define NGR  32
#define TTOT 8192
#define LOG2E  1.4426950408889634f
#define LOG2E2 2.8853900817779268f   // 2*log2(e)
#define KSTRIDE 264                   // LDS floats per transposed key row

__device__ __forceinline__ float dot4(float4 a, float4 b){
  return a.x*b.x + a.y*b.y + a.z*b.z + a.w*b.w;
}
__device__ __forceinline__ float wave_sum64(float x){
  #pragma unroll
  for (int off=32; off>0; off>>=1) x += __shfl_xor(x, off, 64);
  return x;
}
__device__ __forceinline__ float sigfast(float x){
  return __builtin_amdgcn_rcpf(1.f + __builtin_amdgcn_exp2f(-x*LOG2E));
}
__device__ __forceinline__ float tanhfast(float y){
  return 1.f - 2.f*__builtin_amdgcn_rcpf(1.f + __builtin_amdgcn_exp2f(y*LOG2E2));
}
__device__ __forceinline__ float bcast_lane(float v, int lane){
  return __uint_as_float(__builtin_amdgcn_readlane(__float_as_uint(v), lane));
}

// ---------------- Kernel 1: parallel precompute ----------------
// keysE[d][n] = exp(2 * l2norm(relu(emb@Wk1.T+bk1)@Wk2.T+bk2)[n][d])  [128][8192] TRANSPOSED
// gi_all = emb@W_ih.T + b_ih                                          [8192,384]

__device__ __forceinline__ void load_w128(float* Ws, const float* __restrict__ W, int t){
  const float4* src = (const float4*)W;
  #pragma unroll
  for (int m=0;m<16;m++){
    int idx = m*256+t; int r = idx>>5, c4 = idx&31;
    float4 val = src[idx];
    float* dst = &Ws[r*129 + c4*4];
    dst[0]=val.x; dst[1]=val.y; dst[2]=val.z; dst[3]=val.w;
  }
}

__device__ __forceinline__ void mm_tile(const float* __restrict__ inS, const float* __restrict__ Ws,
                                        float acc[4][4], int jg, int ng){
  #pragma unroll
  for(int r=0;r<4;r++)
    #pragma unroll
    for(int c=0;c<4;c++) acc[r][c]=0.f;
  #pragma unroll 4
  for (int k=0;k<128;k++){
    float w[4], x[4];
    #pragma unroll
    for (int r=0;r<4;r++) w[r] = Ws[(jg*4+r)*129+k];
    #pragma unroll
    for (int c=0;c<4;c++) x[c] = inS[(ng*4+c)*129+k];
    #pragma unroll
    for (int r=0;r<4;r++)
      #pragma unroll
      for (int c=0;c<4;c++) acc[r][c] += w[r]*x[c];
  }
}

__global__ __launch_bounds__(256) void precompute_kernel(
    const float* __restrict__ emb,
    const float* __restrict__ Wk1, const float* __restrict__ bk1,
    const float* __restrict__ Wk2, const float* __restrict__ bk2,
    const float* __restrict__ Wih, const float* __restrict__ bih,
    float* __restrict__ keysE, float* __restrict__ giall)
{
  __shared__ __align__(16) float xs[32*129];
  __shared__ __align__(16) float Ws[128*129];
  __shared__ __align__(16) float hs[32*129];
  __shared__ __align__(16) float os[32*129];
  __shared__ float nrm[32];
  const int t  = threadIdx.x;
  const int n0 = blockIdx.x * 32;
  const int ng = t & 7, jg = t >> 3;

  {
    const float4* src = (const float4*)emb + (size_t)n0*32;
    #pragma unroll
    for (int m=0;m<4;m++){
      int idx = m*256+t; int n = idx>>5, c4 = idx&31;
      float4 val = src[idx];
      float* dst = &xs[n*129 + c4*4];
      dst[0]=val.x; dst[1]=val.y; dst[2]=val.z; dst[3]=val.w;
    }
  }
  load_w128(Ws, Wk1, t);
  __syncthreads();
  {
    float acc[4][4];
    mm_tile(xs, Ws, acc, jg, ng);
    #pragma unroll
    for (int r=0;r<4;r++){
      float bb = bk1[jg*4+r];
      #pragma unroll
      for (int c=0;c<4;c++) hs[(ng*4+c)*129 + jg*4+r] = fmaxf(acc[r][c]+bb, 0.f);
    }
  }
  __syncthreads();
  load_w128(Ws, Wk2, t);
  __syncthreads();
  {
    float acc[4][4];
    mm_tile(hs, Ws, acc, jg, ng);
    #pragma unroll
    for (int r=0;r<4;r++){
      float bb = bk2[jg*4+r];
      #pragma unroll
      for (int c=0;c<4;c++) os[(ng*4+c)*129 + jg*4+r] = acc[r][c]+bb;
    }
  }
  __syncthreads();
  if (t<32){
    float ss=0.f;
    for (int j=0;j<128;j++){ float x = os[t*129+j]; ss += x*x; }
    nrm[t] = fmaxf(sqrtf(ss), 1e-12f);
  }
  __syncthreads();
  // transposed E-keys: keysE[d][n] = exp(2*K)
  #pragma unroll
  for (int m=0;m<16;m++){
    int idx = m*256+t; int nl = idx & 31, d = idx >> 5;
    float kk = os[nl*129 + d] / nrm[nl];
    keysE[(size_t)d*TTOT + n0 + nl] = __builtin_amdgcn_exp2f(kk * LOG2E2);
  }
  for (int c=0;c<3;c++){
    __syncthreads();
    load_w128(Ws, Wih + c*16384, t);
    __syncthreads();
    float acc[4][4];
    mm_tile(xs, Ws, acc, jg, ng);
    #pragma unroll
    for (int r=0;r<4;r++){
      float bb = bih[c*128 + jg*4+r];
      #pragma unroll
      for (int cc=0;cc<4;cc++)
        giall[(size_t)(n0 + ng*4+cc)*384 + c*128 + jg*4 + r] = acc[r][cc] + bb;
    }
  }
}

// ---------------- Kernel 2: sequential decode ----------------
// 32 blocks x 1024 threads (16 waves); 255 steps; 5 barriers/step.
// Group g=t>>3 (8 lanes): GRU gate rows {g,128+g,256+g}; Wq1/Wq2 row g.
// 80 register-resident weight floats/lane -> fits 128 VGPRs, no AGPR moves.
// keys in LDS TRANSPOSED [d][n] (stride 264) -> conflict-free b128 score reads.
// tanh(K+q) = 1 - 2/(1+E*eq), E=e^{2K} precomputed, eq=e^{2q} per wave-dim.

__global__ __launch_bounds__(1024) void decode_kernel(
    const float* __restrict__ emb,
    const float* __restrict__ keysE, const float* __restrict__ giall,
    const float* __restrict__ Whh, const float* __restrict__ bhh,
    const float* __restrict__ Wq1, const float* __restrict__ bq1,
    const float* __restrict__ Wq2, const float* __restrict__ bq2,
    const float* __restrict__ v,   const float* __restrict__ Wh,
    const float* __restrict__ bh,  const int* __restrict__ start_nodes,
    float* __restrict__ tours_o, float* __restrict__ lp_o)
{
  __shared__ __align__(16) float keys_s[128*KSTRIDE];  // 132 KB, transposed E-keys
  __shared__ __align__(16) float h_s[2][128];
  __shared__ __align__(16) float qh_s[128];
  __shared__ __align__(16) float q_s[128];
  __shared__ __align__(16) float mask_s[256];          // 0 valid, -inf visited
  __shared__ __align__(16) float spartS[16*256];       // per-wave score partials (also init scratch)
  __shared__ float redv[16]; __shared__ int redi[16]; __shared__ float red2[16];

  const int t = threadIdx.x;
  const int b = blockIdx.x;
  const int g  = t >> 3, s3 = t & 7;   // 128 groups x 8 lanes
  const int w  = t >> 6, L  = t & 63;

  // register weights: Whh rows g,128+g,256+g (chunk s3*16); Wq1/Wq2 row g (chunk s3*16)
  float4 whh4[3][4], wq14[4], wq24[4];
  {
    const float4* w0  = (const float4*)(Whh + (size_t)(g      )*128 + s3*16);
    const float4* w1  = (const float4*)(Whh + (size_t)(128 + g)*128 + s3*16);
    const float4* w2  = (const float4*)(Whh + (size_t)(256 + g)*128 + s3*16);
    const float4* q1p = (const float4*)(Wq1 + (size_t)g*128 + s3*16);
    const float4* q2p = (const float4*)(Wq2 + (size_t)g*128 + s3*16);
    #pragma unroll
    for (int i=0;i<4;i++){
      whh4[0][i]=w0[i]; whh4[1][i]=w1[i]; whh4[2][i]=w2[i];
      wq14[i]=q1p[i];   wq24[i]=q2p[i];
    }
  }
  const float br = bhh[g], bz = bhh[128+g], bn = bhh[256+g];
  const float b1g = bq1[g], b2g = bq2[g];
  float vreg[8];   // -2*v for this wave's 8 dims
  #pragma unroll
  for (int j=0;j<8;j++) vreg[j] = -2.f * v[w*8 + j];

  if (t<256) mask_s[t] = 0.f;
  { // stage transposed E-keys: 8 passes, coalesced per d-row
    #pragma unroll
    for (int m=0;m<8;m++){
      int idx = m*1024 + t; int d = idx>>6, q = idx&63;
      *(float4*)(keys_s + d*KSTRIDE + q*4) =
        *(const float4*)(keysE + (size_t)d*TTOT + b*256 + q*4);
    }
  }
  { // graph-context partial sums (8 parts x 32 nodes)
    int d = t & 127, part = t >> 7;
    float a = 0.f;
    const float* base = emb + (size_t)(b*256 + part*32)*128 + d;
    for (int i=0;i<32;i++) a += base[(size_t)i*128];
    spartS[part*128+d] = a;
  }
  int cur = start_nodes[b];
  __syncthreads();
  if (t<128){
    float a = 0.f;
    #pragma unroll
    for (int p=0;p<8;p++) a += spartS[p*128+t];
    qh_s[t] = a * (1.f/256.f);
  }
  __syncthreads();
  if (t<128){ // hidden0 = gctx@Wh.T + bh
    float a = bh[t];
    const float* wr = Wh + (size_t)t*128;
    for (int k=0;k<128;k++) a += wr[k]*qh_s[k];
    h_s[0][t] = a;
  }
  { // sv = sum(v)
    float xv = (t<128) ? v[t] : 0.f;
    xv = wave_sum64(xv);
    if (L==0) red2[w] = xv;
  }
  __syncthreads();
  float sv = 0.f;
  #pragma unroll
  for (int i=0;i<16;i++) sv += red2[i];

  // gi prefetch for step 0
  float gir=0.f, giz=0.f, gin=0.f;
  if (s3==0){
    const float* gp = giall + (size_t)cur*384 + g;
    gir = gp[0]; giz = gp[128]; gin = gp[256];
  }

  for (int step=0; step<255; step++){
    const int par = step & 1;

    // ---- phase A: gh dots + fused GRU -> h_s[par^1] ----
    if (t==0){
      tours_o[b*256+step] = (float)cur;
      mask_s[cur - b*256] = -INFINITY;
    }
    {
      float a0=0.f,a1=0.f,a2=0.f;
      const float4* hc4 = (const float4*)(h_s[par] + s3*16);
      #pragma unroll
      for (int i=0;i<4;i++){
        float4 hv = hc4[i];
        a0 += dot4(whh4[0][i], hv);
        a1 += dot4(whh4[1][i], hv);
        a2 += dot4(whh4[2][i], hv);
      }
      a0 += __shfl_xor(a0,1,64); a0 += __shfl_xor(a0,2,64); a0 += __shfl_xor(a0,4,64);
      a1 += __shfl_xor(a1,1,64); a1 += __shfl_xor(a1,2,64); a1 += __shfl_xor(a1,4,64);
      a2 += __shfl_xor(a2,1,64); a2 += __shfl_xor(a2,2,64); a2 += __shfl_xor(a2,4,64);
      if (s3==0){
        float r = sigfast(gir + a0 + br);
        float z = sigfast(giz + a1 + bz);
        float n = tanhfast(gin + r*(a2 + bn));
        h_s[par^1][g] = (1.f-z)*n + z*h_s[par][g];
      }
    }
    __syncthreads();                                   // B1

    { // qh = relu(h@Wq1.T + bq1)
      float a=0.f;
      const float4* hc4 = (const float4*)(h_s[par^1] + s3*16);
      #pragma unroll
      for (int i=0;i<4;i++) a += dot4(wq14[i], hc4[i]);
      a += __shfl_xor(a,1,64); a += __shfl_xor(a,2,64); a += __shfl_xor(a,4,64);
      if (s3==0) qh_s[g] = fmaxf(a + b1g, 0.f);
    }
    __syncthreads();                                   // B2

    { // q_raw = qh@Wq2.T + bq2 ; per-wave sum-of-squares partial
      float a=0.f;
      const float4* qc4 = (const float4*)(qh_s + s3*16);
      #pragma unroll
      for (int i=0;i<4;i++) a += dot4(wq24[i], qc4[i]);
      a += __shfl_xor(a,1,64); a += __shfl_xor(a,2,64); a += __shfl_xor(a,4,64);
      float qval = a + b2g;
      if (s3==0) q_s[g] = qval;
      float ssp = (s3==0) ? qval*qval : 0.f;
      ssp = wave_sum64(ssp);
      if (L==0) red2[w] = ssp;
    }
    __syncthreads();                                   // B3

    // ---- score: wave w owns dims w*8..w*8+7; lane L owns positions 4L..4L+3 ----
    {
      float ss = 0.f;
      #pragma unroll
      for (int i=0;i<16;i++) ss += red2[i];
      float rn = 1.f / fmaxf(sqrtf(ss), 1e-12f);
      // eq for dim w*8+(L&7), computed wave-wide (valid in lanes 0..7 and replicas)
      float eq_val = __builtin_amdgcn_exp2f(q_s[w*8 + (L&7)] * rn * LOG2E2);
      float4 acc = {0.f,0.f,0.f,0.f};
      #pragma unroll
      for (int j=0;j<8;j++){
        float eqj = bcast_lane(eq_val, j);
        float4 K = *(const float4*)(keys_s + (w*8+j)*KSTRIDE + L*4);
        float r0 = __builtin_amdgcn_rcpf(fmaf(K.x, eqj, 1.f));
        float r1 = __builtin_amdgcn_rcpf(fmaf(K.y, eqj, 1.f));
        float r2 = __builtin_amdgcn_rcpf(fmaf(K.z, eqj, 1.f));
        float r3 = __builtin_amdgcn_rcpf(fmaf(K.w, eqj, 1.f));
        acc.x = fmaf(vreg[j], r0, acc.x);
        acc.y = fmaf(vreg[j], r1, acc.y);
        acc.z = fmaf(vreg[j], r2, acc.z);
        acc.w = fmaf(vreg[j], r3, acc.w);
      }
      *(float4*)(spartS + w*256 + L*4) = acc;          // conflict-free
    }
    __syncthreads();                                   // Bs1

    // ---- combine + wave-local argmax & softmax stats (threads 0..255) ----
    if (t < 256){
      float sum = 0.f;
      #pragma unroll
      for (int i=0;i<16;i++) sum += spartS[i*256 + t];
      float val = sv + sum + mask_s[t];                // -inf if visited
      int   idx = t;
      float rv = val; int ri = idx;
      #pragma unroll
      for (int off=32; off>0; off>>=1){
        float ov = __shfl_xor(rv, off, 64); int oi = __shfl_xor(ri, off, 64);
        if (ov > rv || (ov == rv && oi < ri)){ rv = ov; ri = oi; }
      }
      float e = (rv == -INFINITY) ? 0.f
              : __builtin_amdgcn_exp2f((val - rv)*LOG2E);
      float Sw = wave_sum64(e);
      if (L==0){ redv[w]=rv; redi[w]=ri; red2[w]=Sw; }
    }
    __syncthreads();                                   // Bs2

    // ---- tail: redundant global argmax, gi prefetch, lp ----
    {
      float m = redv[0]; int besti = redi[0];
      #pragma unroll
      for (int i=1;i<4;i++){
        float ov=redv[i]; int oi=redi[i];
        if (ov > m || (ov==m && oi<besti)){ m=ov; besti=oi; }
      }
      cur = b*256 + besti;
      if (s3==0){   // prefetch next gi (consumed at end of next phase A)
        const float* gp = giall + (size_t)cur*384 + g;
        gir = gp[0]; giz = gp[128]; gin = gp[256];
      }
      if (t==0){
        float sum = 0.f;
        #pragma unroll
        for (int i=0;i<4;i++)
          sum += red2[i] * __builtin_amdgcn_exp2f((redv[i]-m)*LOG2E);
        lp_o[b*255+step] = logf(1.f/sum + 1e-10f);
      }
    }
  }
  if (t==0) tours_o[b*256+255] = (float)cur;
}

extern "C" void kernel_launch(void* const* d_in, const int* in_sizes, int n_in,
                              void* d_out, int out_size, void* d_ws, size_t ws_size,
                              hipStream_t stream) {
  const float* emb  = (const float*)d_in[0];
  const int*   startn = (const int*)d_in[1];
  const float* Wq1 = (const float*)d_in[3];  const float* bq1 = (const float*)d_in[4];
  const float* Wq2 = (const float*)d_in[5];  const float* bq2 = (const float*)d_in[6];
  const float* Wk1 = (const float*)d_in[7];  const float* bk1 = (const float*)d_in[8];
  const float* Wk2 = (const float*)d_in[9];  const float* bk2 = (const float*)d_in[10];
  const float* Wih = (const float*)d_in[11]; const float* Whh = (const float*)d_in[12];
  const float* bih = (const float*)d_in[13]; const float* bhh = (const float*)d_in[14];
  const float* v   = (const float*)d_in[15]; const float* Wh  = (const float*)d_in[16];
  const float* bh  = (const float*)d_in[17];

  float* keysE = (float*)d_ws;               // exp(2*keys) TRANSPOSED [128][8192]
  float* giall = keysE + (size_t)TTOT*DD;    // [8192*384]

  float* outp = (float*)d_out;   // tours [32*256] then log_probs [32*255]

  precompute_kernel<<<256, 256, 0, stream>>>(emb, Wk1, bk1, Wk2, bk2, Wih, bih, keysE, giall);
  decode_kernel<<<NGR, 1024, 0, stream>>>(emb, keysE, giall, Whh, bhh, Wq1, bq1, Wq2, bq2,
                                          v, Wh, bh, startn, outp, outp + TTOT);
}